// Round 10
// baseline (355.681 us; speedup 1.0000x reference)
//
#include <hip/hip_runtime.h>
#include <hip/hip_bf16.h>
#include <math.h>

// Problem constants
#define Bc 2
#define Tc 2048
#define Cc 1024
#define Hc 16
#define Dc 64
// SCALE = 1/8, GAMMA = 8

typedef __attribute__((ext_vector_type(8))) short short8;   // 8 bf16 (4 VGPRs)
typedef __attribute__((ext_vector_type(4))) float f32x4;    // MFMA C/D frag

#define L2E 1.44269504088896f
#define SM_M 20.0f   // fixed softmax shift; |scores| << 20 (std ~0.3)

__device__ __forceinline__ short f2bf(float x) {
    unsigned u = __float_as_uint(x);
    u += 0x7fff + ((u >> 16) & 1);      // RNE
    return (short)(u >> 16);
}
// pack two non-negative floats to bf16 pair (round-half-up) in 3 VALU ops
__device__ __forceinline__ unsigned pack2bf_fast(float a, float b) {
    unsigned ua = __float_as_uint(a) + 0x8000u;
    unsigned ub = __float_as_uint(b) + 0x8000u;
    return __builtin_amdgcn_perm(ub, ua, 0x07060302);  // (ua>>16)|(ub&0xffff0000)
}
// fast softplus: 2 HW transcendentals, ~1e-6 rel err (invisible at bf16)
__device__ __forceinline__ float softplus_fast(float a) {
    return fmaxf(a, 0.f) + __logf(1.f + __expf(-fabsf(a)));
}

// ---------------------------------------------------------------------------
// bf16 MFMA GEMM (m97 recipe): C[M,N] = A[M,K] @ Bt[N,K]^T
// EPI 0: f32 out. EPI 1: bf16 out. EPI 2: fused moire-QK epilogue
// (head-grouped amp|phase column layout; 32B-run stores — R5 rule).
// ---------------------------------------------------------------------------
template <int EPI>
__global__ __launch_bounds__(256) void gemm_bt_mfma(
    const short* __restrict__ A, const short* __restrict__ Bt,
    float* __restrict__ Cf, short* __restrict__ Cb, short* __restrict__ Cb2,
    int M, int N, int K)
{
    __shared__ __attribute__((aligned(16))) short As[128 * 32];
    __shared__ __attribute__((aligned(16))) short Bs[128 * 32];

    const int tid = threadIdx.x;
    const int wave = tid >> 6, lane = tid & 63;
    const int quad = lane >> 4, c = lane & 15;
    const int wm = wave >> 1, wn = wave & 1;
    const int m0 = blockIdx.y * 128, n0 = blockIdx.x * 128;

    const int srow = lane >> 2;
    const int scol = (lane & 3) * 8;
    const short* Ag = A  + (size_t)(m0 + wave * 32 + srow) * K + scol;
    const short* Bg = Bt + (size_t)(n0 + wave * 32 + srow) * K + scol;
    short* AsW = As + (wave * 32) * 32;
    short* BsW = Bs + (wave * 32) * 32;

    f32x4 acc[4][4];
#pragma unroll
    for (int i = 0; i < 4; ++i)
#pragma unroll
        for (int j = 0; j < 4; ++j)
            acc[i][j] = (f32x4){0.f, 0.f, 0.f, 0.f};

    for (int k0 = 0; k0 < K; k0 += 32) {
        __syncthreads();
#pragma unroll
        for (int i = 0; i < 2; ++i) {
            __builtin_amdgcn_global_load_lds(
                (const __attribute__((address_space(1))) void*)(Ag + k0 + (size_t)i * 16 * K),
                (__attribute__((address_space(3))) void*)(AsW + i * 16 * 32), 16, 0, 0);
            __builtin_amdgcn_global_load_lds(
                (const __attribute__((address_space(1))) void*)(Bg + k0 + (size_t)i * 16 * K),
                (__attribute__((address_space(3))) void*)(BsW + i * 16 * 32), 16, 0, 0);
        }
        __syncthreads();

        short8 af[4], bf[4];
#pragma unroll
        for (int mt = 0; mt < 4; ++mt)
            af[mt] = *(const short8*)&As[(wm * 64 + mt * 16 + c) * 32 + quad * 8];
#pragma unroll
        for (int nt = 0; nt < 4; ++nt)
            bf[nt] = *(const short8*)&Bs[(wn * 64 + nt * 16 + c) * 32 + quad * 8];
#pragma unroll
        for (int mt = 0; mt < 4; ++mt)
#pragma unroll
            for (int nt = 0; nt < 4; ++nt)
                acc[mt][nt] = __builtin_amdgcn_mfma_f32_16x16x32_bf16(
                    af[mt], bf[nt], acc[mt][nt], 0, 0, 0);
    }

    if (EPI == 2) {
        const int g = n0 >> 7;                 // 0..31
        const int isK = g >> 4;
        const int h = g & 15;
        const float scl = isK ? 1.f : 0.125f;
        short* dst = isK ? Cb2 : Cb;           // k2 : q2, (B,H,T,128)
#pragma unroll
        for (int mt = 0; mt < 4; ++mt) {
#pragma unroll
            for (int reg = 0; reg < 4; ++reg) {
                int m = m0 + wm * 64 + mt * 16 + quad * 4 + reg;
                int bb = m >> 11, tt = m & (Tc - 1);
                size_t base = (((size_t)bb * Hc + h) * Tc + tt) * 128;
#pragma unroll
                for (int nt = 0; nt < 2; ++nt) {
                    float amp = acc[mt][nt][reg];
                    float ph  = acc[mt][nt + 2][reg];
                    int d = wn * 32 + nt * 16 + c;
                    float sp = softplus_fast(amp) * scl;
                    float sn, cs;
                    __sincosf(ph, &sn, &cs);
                    dst[base + d]      = f2bf(sp * cs);
                    dst[base + d + 64] = f2bf(sp * sn);
                }
            }
        }
    } else {
#pragma unroll
        for (int mt = 0; mt < 4; ++mt) {
#pragma unroll
            for (int reg = 0; reg < 4; ++reg) {
                size_t row = m0 + wm * 64 + mt * 16 + quad * 4 + reg;
#pragma unroll
                for (int nt = 0; nt < 4; ++nt) {
                    size_t col = n0 + wn * 64 + nt * 16 + c;
                    if (EPI == 1) Cb[row * N + col] = f2bf(acc[mt][nt][reg]);
                    else          Cf[row * N + col] = acc[mt][nt][reg];
                }
            }
        }
    }
}

// ---------------------------------------------------------------------------
// V projection fused with head-transpose (unchanged from R9).
// ---------------------------------------------------------------------------
__global__ __launch_bounds__(256) void gemm_v2t(
    const short* __restrict__ A, const short* __restrict__ Bt,
    short* __restrict__ v2t)
{
    __shared__ __attribute__((aligned(16))) short As[128 * 32];
    __shared__ __attribute__((aligned(16))) short Bs[128 * 32];
    __shared__ __attribute__((aligned(16))) short tile[128 * 136];  // [n][t]

    const int K = Cc;
    const int tid = threadIdx.x;
    const int wave = tid >> 6, lane = tid & 63;
    const int quad = lane >> 4, c = lane & 15;
    const int wm = wave >> 1, wn = wave & 1;
    const int m0 = blockIdx.y * 128, n0 = blockIdx.x * 128;

    const int srow = lane >> 2;
    const int scol = (lane & 3) * 8;
    const short* Ag = A  + (size_t)(m0 + wave * 32 + srow) * K + scol;
    const short* Bg = Bt + (size_t)(n0 + wave * 32 + srow) * K + scol;
    short* AsW = As + (wave * 32) * 32;
    short* BsW = Bs + (wave * 32) * 32;

    f32x4 acc[4][4];
#pragma unroll
    for (int i = 0; i < 4; ++i)
#pragma unroll
        for (int j = 0; j < 4; ++j)
            acc[i][j] = (f32x4){0.f, 0.f, 0.f, 0.f};

    for (int k0 = 0; k0 < K; k0 += 32) {
        __syncthreads();
#pragma unroll
        for (int i = 0; i < 2; ++i) {
            __builtin_amdgcn_global_load_lds(
                (const __attribute__((address_space(1))) void*)(Ag + k0 + (size_t)i * 16 * K),
                (__attribute__((address_space(3))) void*)(AsW + i * 16 * 32), 16, 0, 0);
            __builtin_amdgcn_global_load_lds(
                (const __attribute__((address_space(1))) void*)(Bg + k0 + (size_t)i * 16 * K),
                (__attribute__((address_space(3))) void*)(BsW + i * 16 * 32), 16, 0, 0);
        }
        __syncthreads();

        short8 af[4], bf[4];
#pragma unroll
        for (int mt = 0; mt < 4; ++mt)
            af[mt] = *(const short8*)&As[(wm * 64 + mt * 16 + c) * 32 + quad * 8];
#pragma unroll
        for (int nt = 0; nt < 4; ++nt)
            bf[nt] = *(const short8*)&Bs[(wn * 64 + nt * 16 + c) * 32 + quad * 8];
#pragma unroll
        for (int mt = 0; mt < 4; ++mt)
#pragma unroll
            for (int nt = 0; nt < 4; ++nt)
                acc[mt][nt] = __builtin_amdgcn_mfma_f32_16x16x32_bf16(
                    af[mt], bf[nt], acc[mt][nt], 0, 0, 0);
    }

#pragma unroll
    for (int mt = 0; mt < 4; ++mt)
#pragma unroll
        for (int reg = 0; reg < 4; ++reg) {
            int tl = wm * 64 + mt * 16 + quad * 4 + reg;
#pragma unroll
            for (int nt = 0; nt < 4; ++nt)
                tile[(wn * 64 + nt * 16 + c) * 136 + tl] = f2bf(acc[mt][nt][reg]);
        }
    __syncthreads();

    const int b = m0 >> 11, tl0 = m0 & (Tc - 1);
#pragma unroll
    for (int i = 0; i < 8; ++i) {
        int n = i * 16 + (tid >> 4);
        int t8 = (tid & 15) * 8;
        int ng = n0 + n, h = ng >> 6, d = ng & 63;
        *(short8*)&v2t[(((size_t)b * Hc + h) * Dc + d) * Tc + tl0 + t8] =
            *(const short8*)&tile[n * 136 + t8];
    }
}

// ---------------------------------------------------------------------------
__global__ __launch_bounds__(256) void xconv(const float* __restrict__ x,
                                             short* __restrict__ xb)
{
    int idx = blockIdx.x * 256 + threadIdx.x;
    float4 v = *(const float4*)&x[(size_t)idx * 4];
    short4 o = {f2bf(v.x), f2bf(v.y), f2bf(v.z), f2bf(v.w)};
    *(short4*)&xb[(size_t)idx * 4] = o;
}

// ---------------------------------------------------------------------------
// Wq|Wk transpose-convert with the EPI=2 row permutation (unchanged R9).
// ---------------------------------------------------------------------------
__global__ __launch_bounds__(256) void wtrans_qk(const float* __restrict__ Wq,
                                                 const float* __restrict__ Wk,
                                                 short* __restrict__ Bt)
{
    __shared__ short tile[64][80];
    const int n0 = blockIdx.x * 64, k0 = blockIdx.y * 64;
    const int half = blockIdx.z;
    const float* W = half ? Wk : Wq;
    const int tid = threadIdx.x;
#pragma unroll
    for (int i = 0; i < 4; ++i) {
        int e = i * 256 + tid;
        int k = e >> 4, n4 = (e & 15) * 4;
        float4 v = *(const float4*)&W[(size_t)(k0 + k) * 2048 + n0 + n4];
        tile[k][n4]     = f2bf(v.x);
        tile[k][n4 + 1] = f2bf(v.y);
        tile[k][n4 + 2] = f2bf(v.z);
        tile[k][n4 + 3] = f2bf(v.w);
    }
    __syncthreads();
#pragma unroll
    for (int i = 0; i < 16; ++i) {
        int e = i * 256 + tid;
        int n = e >> 6, k = e & 63;
        int ng = n0 + n;
        int sub = ng >> 10, hh = (ng >> 6) & 15, dd = ng & 63;
        int r = (half * 16 + hh) * 128 + (dd >> 5) * 64 + sub * 32 + (dd & 31);
        Bt[(size_t)r * Cc + k0 + k] = tile[k][n];
    }
}

// ---------------------------------------------------------------------------
__global__ __launch_bounds__(256) void wtrans2(const float* __restrict__ Wv,
                                               const float* __restrict__ Wo,
                                               short* __restrict__ WtBase)
{
    __shared__ short tile[64][80];
    const int n0 = blockIdx.x * 64, k0 = blockIdx.y * 64;
    const float* W = blockIdx.z ? Wo : Wv;
    short* Wt = WtBase + (size_t)blockIdx.z * Cc * Cc;
    const int tid = threadIdx.x;
#pragma unroll
    for (int i = 0; i < 4; ++i) {
        int e = i * 256 + tid;
        int k = e >> 4, n4 = (e & 15) * 4;
        float4 v = *(const float4*)&W[(size_t)(k0 + k) * Cc + n0 + n4];
        tile[k][n4]     = f2bf(v.x);
        tile[k][n4 + 1] = f2bf(v.y);
        tile[k][n4 + 2] = f2bf(v.z);
        tile[k][n4 + 3] = f2bf(v.w);
    }
    __syncthreads();
#pragma unroll
    for (int i = 0; i < 16; ++i) {
        int e = i * 256 + tid;
        int n = e >> 6, k = e & 63;
        Wt[(size_t)(n0 + n) * Cc + k0 + k] = tile[k][n];
    }
}

// ---------------------------------------------------------------------------
// MFMA flash attention v6: full wave balance. R9 post-mortem: paired-tile
// split left tx=0 waves idle for jt>p (52% activity at p=0). Fix exploits
// fixed-max softmax associativity over s:
//   phase1 (jt<=p):   waves 0-3 tile 31-p full-s; waves 4-7 tile p full-s
//   phase2 (jt> p):   both teams split tile 31-p s-range (mt 0-1 vs 2-3)
// Upper team reloads qf/gate-base at transition; partial (O,l) merged via
// LDS (Ks reused as f32 scratch) in the epilogue. Every wave active every
// iteration. 512 thr / 8 waves, LDS 64 KB, 2 blocks/CU.
// ---------------------------------------------------------------------------
__global__ __launch_bounds__(512, 4) void moire_attn6(
    const short* __restrict__ q2, const short* __restrict__ k2,
    const short* __restrict__ v2t, const float* __restrict__ theta,
    short* __restrict__ att)
{
    __shared__ __attribute__((aligned(16))) short Ks[2][64 * 128];  // 32 KB
    __shared__ __attribute__((aligned(16))) short Vt[2][64 * 64];   // 16 KB
    __shared__ __attribute__((aligned(16))) short Ps[8][16 * 64];   // 16 KB

    const int tid = threadIdx.x;
    const int wave = tid >> 6, lane = tid & 63;
    const int quad = lane >> 4, c = lane & 15;
    const int g = wave & 3;                 // t-group within tile
    const bool isU = wave >= 4;             // upper team
    const int p = blockIdx.x, h = blockIdx.y, b = blockIdx.z;
    const int pA = p, pB = 31 - p;
    const int q0A = pA * 64, q0B = pB * 64;
    const float th = theta[h];
    const int t_l = g * 16 + c;

    const short* k2b = k2 + (size_t)(b * Hc + h) * Tc * 128;
    const short* v2b = v2t + (size_t)(b * Hc + h) * Dc * Tc;

    // qf: lower team -> tile B (31-p); upper team -> tile A (p), swaps later
    short8 qf[4];
    {
        int q0 = isU ? q0A : q0B;
        const short* qp = q2 + ((size_t)(b * Hc + h) * Tc + q0 + t_l) * 128;
#pragma unroll
        for (int i = 0; i < 4; ++i)
            qf[i] = *(const short8*)(qp + i * 32 + quad * 8);
    }

    // gate*L2E = cb*cOff - sb*sOff; base (cb,sb) = angle th/8*(jt*64-q0-t_l)
    float cb, sb;
    {
        float x0 = th * 0.125f * (float)((isU ? q0A : q0B) + t_l);
        cb = __cosf(x0); sb = -__sinf(x0);
    }
    float cOff[4][4], sOff[4][4];
#pragma unroll
    for (int mt = 0; mt < 4; ++mt)
#pragma unroll
        for (int reg = 0; reg < 4; ++reg) {
            float a = th * 0.125f * (float)(mt * 16 + quad * 4 + reg);
            cOff[mt][reg] = __cosf(a) * L2E;
            sOff[mt][reg] = __sinf(a) * L2E;
        }
    const float cD = __cosf(8.f * th), sD = __sinf(8.f * th);

    f32x4 oacc[4];    // L: O(tile B); U: O(tile A)
    f32x4 oacc2[4];   // U only: O(tile B) partial (s upper half)
    float lsum = 0.f, lsum2 = 0.f;
#pragma unroll
    for (int nt = 0; nt < 4; ++nt) {
        oacc[nt]  = (f32x4){0.f, 0.f, 0.f, 0.f};
        oacc2[nt] = (f32x4){0.f, 0.f, 0.f, 0.f};
    }

    auto stage = [&](int jts) {
        short* KsB = &Ks[jts & 1][0];
        short* VtB = &Vt[jts & 1][0];
        const int s0 = jts * 64;
#pragma unroll
        for (int i = 0; i < 2; ++i) {          // Ks: 1024 16B chunks
            int ch = i * 512 + tid;
            int row = ch >> 4, j = ch & 15;
            const short* src = k2b + (size_t)(s0 + row) * 128 + ((j ^ (row & 15)) << 3);
            __builtin_amdgcn_global_load_lds(
                (const __attribute__((address_space(1))) void*)src,
                (__attribute__((address_space(3))) void*)(KsB + (i * 512 + wave * 64) * 8),
                16, 0, 0);
        }
        {                                       // Vt: 512 16B chunks
            int ch = tid;
            int row = ch >> 3, j = ch & 7;
            const short* src = v2b + (size_t)row * Tc + s0 + ((j ^ (row & 7)) << 3);
            __builtin_amdgcn_global_load_lds(
                (const __attribute__((address_space(1))) void*)src,
                (__attribute__((address_space(3))) void*)(VtB + (wave * 64) * 8),
                16, 0, 0);
        }
    };

    // one s-half (hh=0: mt 0-1 / s 0-31 / kk=0; hh=1: mt 2-3 / s 32-63 / kk=1)
    auto doHalf = [&](int hh, bool diag, f32x4* oa, float& ls,
                      const short* KsB, const short* VtB) {
        f32x4 s_acc[2];
#pragma unroll
        for (int m2 = 0; m2 < 2; ++m2) {
            int mt = hh * 2 + m2;
            f32x4 a = {0.f, 0.f, 0.f, 0.f};
#pragma unroll
            for (int kk = 0; kk < 4; ++kk) {
                short8 kf = *(const short8*)&KsB[(mt * 16 + c) * 128 +
                                                 (((kk * 4 + quad) ^ c) << 3)];
                a = __builtin_amdgcn_mfma_f32_16x16x32_bf16(kf, qf[kk], a, 0, 0, 0);
            }
            s_acc[m2] = a;
        }
#pragma unroll
        for (int m2 = 0; m2 < 2; ++m2) {
            int mt = hh * 2 + m2;
            float pv[4];
#pragma unroll
            for (int reg = 0; reg < 4; ++reg) {
                float g2 = cb * cOff[mt][reg] - sb * sOff[mt][reg];
                float arg = fmaf(s_acc[m2][reg], g2, -SM_M * L2E);
                if (diag && (mt * 16 + quad * 4 + reg) > t_l) arg = -1e30f;
                pv[reg] = exp2f(arg);
            }
            ls += (pv[0] + pv[1]) + (pv[2] + pv[3]);
            uint2 pk = {pack2bf_fast(pv[0], pv[1]), pack2bf_fast(pv[2], pv[3])};
            int slot = ((mt * 2 + (quad >> 1)) ^ (c & 7));
            *(uint2*)&Ps[wave][c * 64 + slot * 8 + (quad & 1) * 4] = pk;
        }
        short8 pf = *(const short8*)&Ps[wave][c * 64 +
                         (((hh * 4 + quad) ^ (c & 7)) << 3)];
#pragma unroll
        for (int nt = 0; nt < 4; ++nt) {
            short8 vf = *(const short8*)&VtB[(nt * 16 + c) * 64 +
                         (((hh * 4 + quad) ^ (c & 7)) << 3)];
            oa[nt] = __builtin_amdgcn_mfma_f32_16x16x32_bf16(pf, vf, oa[nt], 0, 0, 0);
        }
    };

    stage(0);
    for (int jt = 0; jt <= pB; ++jt) {
        __syncthreads();
        if (jt < pB) stage(jt + 1);
        const short* KsB = &Ks[jt & 1][0];
        const short* VtB = &Vt[jt & 1][0];

        if (isU && jt == pA + 1) {
            // upper team switches to tile B (s upper half duty)
            const short* qp = q2 + ((size_t)(b * Hc + h) * Tc + q0B + t_l) * 128;
#pragma unroll
            for (int i = 0; i < 4; ++i)
                qf[i] = *(const short8*)(qp + i * 32 + quad * 8);
            float xx = th * 0.125f * (float)(jt * 64 - q0B - t_l);
            cb = __cosf(xx); sb = __sinf(xx);
        }

        if (jt <= pA) {
            bool diag = isU && (jt == pA);      // tile A diagonal
            doHalf(0, diag, oacc, lsum, KsB, VtB);
            doHalf(1, diag, oacc, lsum, KsB, VtB);
        } else {
            bool diag = (jt == pB);             // tile B diagonal
            if (!isU) doHalf(0, diag, oacc,  lsum,  KsB, VtB);
            else      doHalf(1, diag, oacc2, lsum2, KsB, VtB);
        }

        // advance base angle one tile
        float ncb = cb * cD - sb * sD;
        sb = sb * cD + cb * sD;
        cb = ncb;
    }

    // ---- epilogue: merge tile-B partials (U -> L via LDS), write both tiles
    __syncthreads();
    float* Ox = (float*)&Ks[0][0];    // 4 U-waves x 16t x 64d f32 (pitch 65)
    float* Lx = (float*)&Vt[0][0];    // 4 x 16 lsum partials

    if (isU) {
        float l2 = lsum2;
        l2 += __shfl_xor(l2, 16);
        l2 += __shfl_xor(l2, 32);
        Lx[g * 16 + c] = l2;
#pragma unroll
        for (int nt = 0; nt < 4; ++nt)
#pragma unroll
            for (int reg = 0; reg < 4; ++reg)
                Ox[g * 1040 + (quad * 4 + reg) * 65 + nt * 16 + c] = oacc2[nt][reg];
    }
    __syncthreads();

    if (!isU) {
        float l = lsum;
        l += __shfl_xor(l, 16);
        l += __shfl_xor(l, 32);
        l += Lx[g * 16 + c];
        float il = 1.f / l;
        float ilr[4];
#pragma unroll
        for (int reg = 0; reg < 4; ++reg)
            ilr[reg] = __shfl(il, quad * 4 + reg);
#pragma unroll
        for (int reg = 0; reg < 4; ++reg) {
            int t_g = q0B + g * 16 + quad * 4 + reg;
#pragma unroll
            for (int nt = 0; nt < 4; ++nt) {
                float o = oacc[nt][reg] +
                          Ox[g * 1040 + (quad * 4 + reg) * 65 + nt * 16 + c];
                att[(size_t)(b * Tc + t_g) * Cc + h * Dc + nt * 16 + c] =
                    f2bf(o * ilr[reg]);
            }
        }
    } else {
        float l = lsum;
        l += __shfl_xor(l, 16);
        l += __shfl_xor(l, 32);
        float il = 1.f / l;
        float ilr[4];
#pragma unroll
        for (int reg = 0; reg < 4; ++reg)
            ilr[reg] = __shfl(il, quad * 4 + reg);
#pragma unroll
        for (int reg = 0; reg < 4; ++reg) {
            int t_g = q0A + g * 16 + quad * 4 + reg;
#pragma unroll
            for (int nt = 0; nt < 4; ++nt)
                att[(size_t)(b * Tc + t_g) * Cc + h * Dc + nt * 16 + c] =
                    f2bf(oacc[nt][reg] * ilr[reg]);
        }
    }
}

// ---------------------------------------------------------------------------
extern "C" void kernel_launch(void* const* d_in, const int* in_sizes, int n_in,
                              void* d_out, int out_size, void* d_ws, size_t ws_size,
                              hipStream_t stream)
{
    const float* x     = (const float*)d_in[0];
    const float* Wq    = (const float*)d_in[1];
    const float* Wk    = (const float*)d_in[2];
    const float* Wv    = (const float*)d_in[3];
    const float* Wo    = (const float*)d_in[4];
    const float* theta = (const float*)d_in[5];
    float* out = (float*)d_out;

    const int M = Bc * Tc;                 // 4096
    char* ws = (char*)d_ws;
    const size_t MB = 1 << 20;
    short* xb   = (short*)(ws);             // [0,8)   x bf16
    short* Bqk  = (short*)(ws + 8 * MB);    // [8,16)  permuted [Wq'|Wk']^T bf16
    short* Wvt  = (short*)(ws + 16 * MB);   // [16,18)
    short* Wot  = (short*)(ws + 18 * MB);   // [18,20)
    short* v2t  = (short*)(ws + 28 * MB);   // [28,36) bf16 (B,H,D,T)
    short* attb = (short*)(ws + 36 * MB);   // [36,44)
    short* q2   = (short*)(ws + 44 * MB);   // [44,60) bf16 (B,H,T,128)
    short* k2   = (short*)d_out;            // 16 MB   bf16 (B,H,T,128) until final gemm

    xconv<<<(size_t)M * Cc / 1024, 256, 0, stream>>>(x, xb);
    wtrans_qk<<<dim3(2048 / 64, Cc / 64, 2), 256, 0, stream>>>(Wq, Wk, Bqk);
    wtrans2<<<dim3(Cc / 64, Cc / 64, 2), 256, 0, stream>>>(Wv, Wo, Wvt);

    // fused QK projection + moire transform (writes q2, k2 directly)
    gemm_bt_mfma<2><<<dim3(4096 / 128, M / 128), 256, 0, stream>>>(
        xb, Bqk, nullptr, q2, k2, M, 4096, Cc);
    // fused V projection + head-transpose (writes v2t directly)
    gemm_v2t<<<dim3(Cc / 128, M / 128), 256, 0, stream>>>(xb, Wvt, v2t);

    moire_attn6<<<dim3(16, Hc, Bc), 512, 0, stream>>>(q2, k2, v2t, theta, attb);

    gemm_bt_mfma<0><<<dim3(Cc / 128, M / 128), 256, 0, stream>>>(
        attb, Wot, out, nullptr, nullptr, M, Cc, Cc);
}